// Round 5
// baseline (9361.847 us; speedup 1.0000x reference)
//
#include <hip/hip_runtime.h>
#include <stdint.h>

// Problem constants
#define VOCAB 50000
#define EMBD  128
#define HID   256
#define G4    1024   // 4*HID
#define BATCH 256
#define TSEQ  512
#define OUTD  64

typedef __attribute__((ext_vector_type(4))) float f32x4;
typedef __attribute__((ext_vector_type(8))) short short8;
typedef __attribute__((ext_vector_type(4))) unsigned short ushort4_t;

__device__ inline unsigned short f2bf(float f) {
  unsigned u = __float_as_uint(f);
  u += 0x7fffu + ((u >> 16) & 1u);     // round-nearest-even
  return (unsigned short)(u >> 16);
}
__device__ inline float bf2f(unsigned short u) {
  return __uint_as_float(((unsigned)u) << 16);
}
__device__ inline short8 pack2(f32x4 a, f32x4 b) {
  short8 r;
  r[0] = (short)f2bf(a[0]); r[1] = (short)f2bf(a[1]);
  r[2] = (short)f2bf(a[2]); r[3] = (short)f2bf(a[3]);
  r[4] = (short)f2bf(b[0]); r[5] = (short)f2bf(b[1]);
  r[6] = (short)f2bf(b[2]); r[7] = (short)f2bf(b[3]);
  return r;
}

// LDS-only barrier: h double-buffer needs only LDS ordering; global prefetch
// loads stay in flight across it.
__device__ inline void barrier_lds_only() {
  asm volatile("s_waitcnt lgkmcnt(0)\n\ts_barrier" ::: "memory");
}

// ---------------------------------------------------------------------------
// K1: Wx[v][u*4+nt] = bf16( b_ih[oj] + b_hh[oj] + emb[v] . W_ih[oj] )
// (unchanged)
// ---------------------------------------------------------------------------
__global__ __launch_bounds__(256) void wx_k1(
    const float* __restrict__ emb, const float* __restrict__ Wih,
    const float* __restrict__ bih, const float* __restrict__ bhh,
    unsigned short* __restrict__ Wx) {
  const int w1 = threadIdx.x >> 6, lane = threadIdx.x & 63;
  const int quad = lane >> 4, n = lane & 15;
  const int combo = blockIdx.y * 4 + w1;        // 0..15 -> units combo*16..+15

  float bias[4];
  short8 bfr[4][4];
#pragma unroll
  for (int nt = 0; nt < 4; ++nt) {
    const int oj = nt * 256 + combo * 16 + n;
    bias[nt] = bih[oj] + bhh[oj];
#pragma unroll
    for (int kc = 0; kc < 4; ++kc) {
      const f32x4* wp = (const f32x4*)(Wih + (size_t)oj * EMBD + kc * 32 + quad * 8);
      bfr[nt][kc] = pack2(wp[0], wp[1]);
    }
  }

  for (int vt = 0; vt < 4; ++vt) {
    const int vb = blockIdx.x * 64 + vt * 16;
    if (vb >= VOCAB) break;                     // tiles align: 49,984+16 = 50,000
    short8 af[4];
#pragma unroll
    for (int kc = 0; kc < 4; ++kc) {
      const f32x4* ep = (const f32x4*)(emb + (size_t)(vb + n) * EMBD + kc * 32 + quad * 8);
      af[kc] = pack2(ep[0], ep[1]);
    }
    f32x4 acc[4];
#pragma unroll
    for (int nt = 0; nt < 4; ++nt) acc[nt] = (f32x4){0.f, 0.f, 0.f, 0.f};
#pragma unroll
    for (int kc = 0; kc < 4; ++kc)
#pragma unroll
      for (int nt = 0; nt < 4; ++nt)
        acc[nt] = __builtin_amdgcn_mfma_f32_16x16x32_bf16(af[kc], bfr[nt][kc], acc[nt], 0, 0, 0);
#pragma unroll
    for (int rr = 0; rr < 4; ++rr) {
      ushort4_t o;
#pragma unroll
      for (int nt = 0; nt < 4; ++nt) o[nt] = f2bf(acc[nt][rr] + bias[nt]);
      *(ushort4_t*)&Wx[(size_t)(vb + quad * 4 + rr) * G4 + (combo * 16 + n) * 4] = o;
    }
  }
}

// ---------------------------------------------------------------------------
// K2: LSTM recurrence, R15 island-pair split.
// 128 WGs = 64 islands (4 batch rows each) x 2 halves. Half owns 128 units
// (512 of 1024 gate-cols): ALL its Whh columns fit in 128 regs/lane -> wlds
// deleted, zero B-LDS traffic, per-CU MFMA count halved (256 -> 32/wave).
// Pair exchange of h halves per step through workspace (L2):
//  - pairing bid^64 keeps both halves on one XCD (bid%8 equal).
//  - own-first K ordering: partner h(t) consumed only by the LAST 4 K-chunks;
//    it was posted a full step earlier -> spin expected to hit immediately.
//  - protocol: per-wave vmcnt(0) after data stores, then lane0 release-add
//    on cnt[bid] (8 adds/step). Reader spins acquire-load cnt[partner]>=8t,
//    courier-loads partner data as relaxed-agent uint loads (L1 bypass).
//  - skew bound: posting into buf[(t+1)&1] overwrites h(t-1); partner proved
//    (by its cnt>=8t) it finished step t-1, whose [F] vmcnt(0) drained its
//    loads of h(t-1). Double-buffer is race-free.
//  - Wx prefetch 2-deep (wxA/wxB ping-pong, static unroll-2): issued AFTER
//    the [F] vmcnt(0), so the drain never waits on a fresh Wx load, and each
//    load gets ~2 steps of flight before use.
//  - spin timeout -> graceful wrong answer instead of hang.
// Carried: broadcast-A, XOR-toggled h base, LDS token offsets, __expf
// pointwise (no inline-asm trans ops).
// ---------------------------------------------------------------------------
__global__ __launch_bounds__(512, 2) void lstm_k2(
    const int* __restrict__ x, const float* __restrict__ Whh,
    const unsigned short* __restrict__ Wx,
    float* __restrict__ lastH,                 // [256][256]
    unsigned short* __restrict__ exch,         // [64][2][2][512] bf16
    int* __restrict__ cnt) {                   // [128], zeroed per launch
  const int bid = blockIdx.x;
  const int island = bid & 63, half = bid >> 6;
  const int rowbase = island * 4;
  const int tid = threadIdx.x;
  const int w = tid >> 6, lane = tid & 63;
  const int quad = lane >> 4, n = lane & 15;
  const int U0 = half * 128, U0p = (half ^ 1) * 128;

  __shared__ __attribute__((aligned(16))) unsigned short h_lds[2][16][264];   // 16.5 KB
  __shared__ int xoff[4][TSEQ];                // 8 KB, prescaled token offsets
  __shared__ int zpos[4];

  if (tid < 4) zpos[tid] = 1 << 30;
  __syncthreads();
  for (int i = tid; i < 4 * TSEQ; i += 512) {
    const int row = i >> 9, tc = i & 511;
    const int tok = x[(size_t)(rowbase + row) * TSEQ + tc];
    if (tok == 0) atomicMin(&zpos[row], tc);
    xoff[row][tc] = tok * G4;
  }
  // zero BOTH h buffers (rows 0,4,8,12 hold h(0)=0; row 1 = broadcast-zero)
  for (int i = tid; i < 2 * 16 * 264; i += 512) ((unsigned short*)h_lds)[i] = 0;

  // all-register weights for our 512 cols, own-first K-chunk order:
  // bfr[nt][j] holds global K-chunk (half*4 + j) & 7.
  short8 bfr[4][8];
#pragma unroll
  for (int nt = 0; nt < 4; ++nt) {
    const int oj = nt * 256 + U0 + w * 16 + n;
    const float* wrow = Whh + (size_t)oj * HID;
#pragma unroll
    for (int j = 0; j < 8; ++j) {
      const int kcg = (half * 4 + j) & 7;
      const f32x4* wp = (const f32x4*)(wrow + kcg * 32 + quad * 8);
      bfr[nt][j] = pack2(wp[0], wp[1]);
    }
  }

  float cst = 0.f;
  __syncthreads();   // zpos, xoff, h(0) ready
  const int idxq = zpos[quad] - 1;

  // per-lane constant byte offsets
  const int ard = ((n & 3) == 0) ? (n * 528 + quad * 16) : 528;
  const int ard_own = ard + half * 256;          // own K-chunks  (units U0..)
  const int ard_par = ard + (half ^ 1) * 256;    // partner K-chunks
  const int awr = quad * 2112 + (U0 + w * 16 + n) * 2;
  const unsigned lanewx = (unsigned)((U0 + w * 16 + n) * 4);
  char* hb = (char*)&h_lds[0][0][0];
  unsigned hoff = 0;

  int* cnt_me = cnt + bid;
  int* cnt_pt = cnt + (bid ^ 64);

  // 2-deep Wx prefetch
  ushort4_t wxA = *(const ushort4_t*)(Wx + (size_t)(unsigned)xoff[quad][0] + lanewx);
  ushort4_t wxB = *(const ushort4_t*)(Wx + (size_t)(unsigned)xoff[quad][1] + lanewx);

  auto step = [&](int t, ushort4_t& wxc) {
    // [A] courier: waves 0..3 spin for partner h(t), then load their slice
    unsigned cour = 0;
    const bool docour = (t > 0) && (tid < 256);
    if (docour) {
      const int tgt = 8 * t;
      int guard = 0;
      while (__hip_atomic_load(cnt_pt, __ATOMIC_ACQUIRE, __HIP_MEMORY_SCOPE_AGENT) < tgt) {
        if (++guard > (1 << 16)) break;        // graceful fail, never hang
        __builtin_amdgcn_s_sleep(2);
      }
      const unsigned* src =
          (const unsigned*)(exch + (((island * 2 + (t & 1)) * 2 + (half ^ 1)) << 9));
      cour = __hip_atomic_load((unsigned*)(src + tid),
                               __ATOMIC_RELAXED, __HIP_MEMORY_SCOPE_AGENT);
    }

    // [B] acc init from prefetched Wx; own-half K MFMAs (h_own(t) is local)
    f32x4 acc[4];
#pragma unroll
    for (int nt = 0; nt < 4; ++nt)
      acc[nt] = (f32x4){bf2f(wxc[nt]), 0.f, 0.f, 0.f};
#pragma unroll
    for (int j = 0; j < 4; ++j) {
      const short8 a = *(const short8*)(hb + hoff + ard_own + j * 64);
#pragma unroll
      for (int nt = 0; nt < 4; ++nt)
        acc[nt] = __builtin_amdgcn_mfma_f32_16x16x32_bf16(a, bfr[nt][j], acc[nt], 0, 0, 0);
    }

    // token offset for t+2 (LDS broadcast read)
    const int tnn = (t + 2 < TSEQ) ? (t + 2) : (TSEQ - 1);
    const int tok2 = xoff[quad][tnn];

    // [C] courier data -> LDS (current h buffer, partner half), then barrier
    if (docour)
      *(unsigned*)(hb + hoff + ((tid >> 6) * 4) * 528 + (U0p + ((2 * tid) & 127)) * 2) = cour;
    barrier_lds_only();

    // [D] partner-half K MFMAs
#pragma unroll
    for (int j = 0; j < 4; ++j) {
      const short8 a = *(const short8*)(hb + hoff + ard_par + j * 64);
#pragma unroll
      for (int nt = 0; nt < 4; ++nt)
        acc[nt] = __builtin_amdgcn_mfma_f32_16x16x32_bf16(a, bfr[nt][4 + j], acc[nt], 0, 0, 0);
    }

    // [E] fused pointwise (R8-validated): one (row=quad, unit) per lane
    const float ei = __expf(-acc[0][0]), ef = __expf(-acc[1][0]);
    const float eg2 = __expf(2.0f * acc[2][0]), eo = __expf(-acc[3][0]);
    const float r1 = __builtin_amdgcn_rcpf(1.0f + ef);
    const float r2 = __builtin_amdgcn_rcpf((1.0f + ei) * (eg2 + 1.0f));
    const float ci = cst * r1 + (eg2 - 1.0f) * r2;
    cst = ci;
    const float ec2 = __expf(2.0f * ci);
    const float r3 = __builtin_amdgcn_rcpf((1.0f + eo) * (ec2 + 1.0f));
    const float hv = (ec2 - 1.0f) * r3;
    const unsigned short h16 = f2bf(hv);

    // [F] own h(t+1) -> LDS next buf; exchange post; flag; Wx prefetch t+2
    *(unsigned short*)(hb + (hoff ^ 8448u) + awr) = h16;
    exch[(((island * 2 + ((t + 1) & 1)) * 2 + half) << 9) + quad * 128 + w * 16 + n] = h16;
    if (t == idxq)
      lastH[(size_t)(rowbase + quad) * HID + U0 + w * 16 + n] = hv;
    asm volatile("s_waitcnt vmcnt(0)" ::: "memory");   // data visible pre-flag
    if (lane == 0)
      __hip_atomic_fetch_add(cnt_me, 1, __ATOMIC_RELEASE, __HIP_MEMORY_SCOPE_AGENT);
    wxc = *(const ushort4_t*)(Wx + (size_t)(unsigned)tok2 + lanewx);

    // [G] step barrier (lgkm only; Wx prefetch stays in flight)
    hoff ^= 8448u;
    barrier_lds_only();
  };

  for (int t2 = 0; t2 < TSEQ / 2; ++t2) {
    step(2 * t2, wxA);
    step(2 * t2 + 1, wxB);
  }
}

// ---------------------------------------------------------------------------
// K3: logits + softmax. One wave per batch row; lane j = output j.
// ---------------------------------------------------------------------------
__global__ __launch_bounds__(64) void head_k3(
    const float* __restrict__ lastH, const float* __restrict__ Wout,
    const float* __restrict__ bout, float* __restrict__ out) {
  const int b = blockIdx.x, j = threadIdx.x;
  const f32x4* hv = (const f32x4*)(lastH + (size_t)b * HID);
  const f32x4* wv = (const f32x4*)(Wout + (size_t)j * HID);
  float acc = bout[j];
#pragma unroll 8
  for (int k = 0; k < HID / 4; ++k) {
    const f32x4 a = hv[k], ww = wv[k];
    acc += a[0] * ww[0] + a[1] * ww[1] + a[2] * ww[2] + a[3] * ww[3];
  }
  float m = acc;
  for (int s = 32; s > 0; s >>= 1) m = fmaxf(m, __shfl_xor(m, s, 64));
  const float e = __expf(acc - m);
  float ssum = e;
  for (int s = 32; s > 0; s >>= 1) ssum += __shfl_xor(ssum, s, 64);
  out[(size_t)b * OUTD + j] = e / ssum;
}

// ---------------------------------------------------------------------------
extern "C" void kernel_launch(void* const* d_in, const int* in_sizes, int n_in,
                              void* d_out, int out_size, void* d_ws, size_t ws_size,
                              hipStream_t stream) {
  const int*   x    = (const int*)d_in[0];
  const float* emb  = (const float*)d_in[1];
  const float* Wih  = (const float*)d_in[2];
  const float* Whh  = (const float*)d_in[3];
  const float* bih  = (const float*)d_in[4];
  const float* bhh  = (const float*)d_in[5];
  const float* Wout = (const float*)d_in[6];
  const float* bout = (const float*)d_in[7];
  float* out = (float*)d_out;

  // workspace carve (~98.2 MiB)
  char* ws = (char*)d_ws;
  unsigned short* Wx = (unsigned short*)ws;                     // 102,400,000 B
  float* lastH = (float*)(ws + 102400000);                      //     262,144 B
  unsigned short* exch = (unsigned short*)(ws + 102662144);     //     262,144 B
  int* cnt = (int*)(ws + 102924288);                            //         512 B

  hipMemsetAsync(cnt, 0, 512, stream);   // flags must start at 0 each launch
  hipLaunchKernelGGL(wx_k1, dim3(782, 4), dim3(256), 0, stream,
                     emb, Wih, bih, bhh, Wx);
  hipLaunchKernelGGL(lstm_k2, dim3(128), dim3(512), 0, stream,
                     x, Whh, Wx, lastH, exch, cnt);
  hipLaunchKernelGGL(head_k3, dim3(BATCH), dim3(OUTD), 0, stream,
                     lastH, Wout, bout, out);
}

// Round 6
// 1036.393 us; speedup vs baseline: 9.0331x; 9.0331x over previous
//
#include <hip/hip_runtime.h>
#include <stdint.h>

// Problem constants
#define VOCAB 50000
#define EMBD  128
#define HID   256
#define G4    1024   // 4*HID
#define BATCH 256
#define TSEQ  512
#define OUTD  64

typedef __attribute__((ext_vector_type(4))) float f32x4;
typedef __attribute__((ext_vector_type(8))) short short8;
typedef __attribute__((ext_vector_type(4))) unsigned short ushort4_t;
typedef __attribute__((ext_vector_type(8))) unsigned short ushort8_t;

__device__ inline unsigned short f2bf(float f) {
  unsigned u = __float_as_uint(f);
  u += 0x7fffu + ((u >> 16) & 1u);     // round-nearest-even
  return (unsigned short)(u >> 16);
}
__device__ inline float bf2f(unsigned short u) {
  return __uint_as_float(((unsigned)u) << 16);
}
__device__ inline short8 pack2(f32x4 a, f32x4 b) {
  short8 r;
  r[0] = (short)f2bf(a[0]); r[1] = (short)f2bf(a[1]);
  r[2] = (short)f2bf(a[2]); r[3] = (short)f2bf(a[3]);
  r[4] = (short)f2bf(b[0]); r[5] = (short)f2bf(b[1]);
  r[6] = (short)f2bf(b[2]); r[7] = (short)f2bf(b[3]);
  return r;
}

// LDS-only barrier: h double-buffer needs only LDS ordering; global prefetch
// loads stay in flight across it.
__device__ inline void barrier_lds_only() {
  asm volatile("s_waitcnt lgkmcnt(0)\n\ts_barrier" ::: "memory");
}

// Wx layout: Wx[v][u*4 + nt], u = h-unit, nt in {i,f,g,o}; oj = nt*256 + u.
// K2 unit mapping u = w*32 + 2n + gl (adjacent gl outputs -> one packed b32
// h-write, one coalesced 16B Wx prefetch per lane).

// ---------------------------------------------------------------------------
// K1: Wx[v][u*4+nt] = bf16( b_ih[oj] + b_hh[oj] + emb[v] . W_ih[oj] )
// R16: 16 vocab tiles per block (was 4), grid (196,4) = 784 blocks — the
// per-block W_ih fragment pack (384 ops/thread) amortizes 4x better; inner
// loop identical. 195*256=49,920; block 195 covers the 80-row tail (break).
// ---------------------------------------------------------------------------
__global__ __launch_bounds__(256) void wx_k1(
    const float* __restrict__ emb, const float* __restrict__ Wih,
    const float* __restrict__ bih, const float* __restrict__ bhh,
    unsigned short* __restrict__ Wx) {
  const int w1 = threadIdx.x >> 6, lane = threadIdx.x & 63;
  const int quad = lane >> 4, n = lane & 15;
  const int combo = blockIdx.y * 4 + w1;        // 0..15 -> units combo*16..+15

  float bias[4];
  short8 bfr[4][4];
#pragma unroll
  for (int nt = 0; nt < 4; ++nt) {
    const int oj = nt * 256 + combo * 16 + n;
    bias[nt] = bih[oj] + bhh[oj];
#pragma unroll
    for (int kc = 0; kc < 4; ++kc) {
      const f32x4* wp = (const f32x4*)(Wih + (size_t)oj * EMBD + kc * 32 + quad * 8);
      bfr[nt][kc] = pack2(wp[0], wp[1]);
    }
  }

  for (int vt = 0; vt < 16; ++vt) {
    const int vb = blockIdx.x * 256 + vt * 16;
    if (vb >= VOCAB) break;                     // tail block: 49,920+5*16 = 50,000
    short8 af[4];
#pragma unroll
    for (int kc = 0; kc < 4; ++kc) {
      const f32x4* ep = (const f32x4*)(emb + (size_t)(vb + n) * EMBD + kc * 32 + quad * 8);
      af[kc] = pack2(ep[0], ep[1]);
    }
    f32x4 acc[4];
#pragma unroll
    for (int nt = 0; nt < 4; ++nt) acc[nt] = (f32x4){0.f, 0.f, 0.f, 0.f};
#pragma unroll
    for (int kc = 0; kc < 4; ++kc)
#pragma unroll
      for (int nt = 0; nt < 4; ++nt)
        acc[nt] = __builtin_amdgcn_mfma_f32_16x16x32_bf16(af[kc], bfr[nt][kc], acc[nt], 0, 0, 0);
#pragma unroll
    for (int rr = 0; rr < 4; ++rr) {
      ushort4_t o;
#pragma unroll
      for (int nt = 0; nt < 4; ++nt) o[nt] = f2bf(acc[nt][rr] + bias[nt]);
      *(ushort4_t*)&Wx[(size_t)(vb + quad * 4 + rr) * G4 + (combo * 16 + n) * 4] = o;
    }
  }
}

// ---------------------------------------------------------------------------
// K2: LSTM recurrence — byte-identical to R13 (measured 892 us), which is the
// capacity optimum for this decomposition:
//  - R14 lesson: all-register Whh needs 256+32 regs > the 256/wave unified
//    cap at 2 waves/SIMD -> scratch spill (2.4x regression). Full Whh
//    (512 KB) equals the entire per-CU register file; 6-in-reg/2-in-LDS is
//    the best split.
//  - R15 lesson: per-step cross-WG exchange is unaffordable — per-XCD L2s
//    are non-coherent, so agent-scope release/acquire forces HBM-class
//    round trips every step (10x regression).
// Structure: 64 WGs x 512 thr; WG = 4 batch rows, all 256 units, one
// lgkm-only barrier/step; broadcast-A (phantom lanes read always-zero row 1);
// unit remap u=w*32+2n+gl; XOR-toggled h base; LDS-staged token offsets;
// __expf pointwise (R12 lesson: no inline-asm trans ops).
// ---------------------------------------------------------------------------
__global__ __launch_bounds__(512, 2) void lstm_k2(
    const int* __restrict__ x, const float* __restrict__ Whh,
    const unsigned short* __restrict__ Wx,
    float* __restrict__ lastH) {               // [256][256]
  const int group = blockIdx.x;                // 64 groups of 4 batch rows
  const int rowbase = group * 4;
  const int tid = threadIdx.x;
  const int w = tid >> 6, lane = tid & 63;
  const int quad = lane >> 4, n = lane & 15;

  __shared__ __attribute__((aligned(16))) unsigned short h_lds[2][16][264];   // 16.5 KB
  __shared__ __attribute__((aligned(16))) unsigned short wlds[8][2][4][2][64][8]; // 128 KB
  __shared__ int xoff[4][TSEQ];                // 8 KB, prescaled token offsets
  __shared__ int zpos[4];

  if (tid < 4) zpos[tid] = 1 << 30;
  __syncthreads();
  // scan tokens: pad position + stage prescaled Wx row offsets in LDS
  for (int i = tid; i < 4 * TSEQ; i += 512) {
    const int row = i >> 9, tc = i & 511;
    const int tok = x[(size_t)(rowbase + row) * TSEQ + tc];
    if (tok == 0) atomicMin(&zpos[row], tc);
    xoff[row][tc] = tok * G4;
  }
  // zero BOTH h buffers (real rows 0,4,8,12 need h(0)=0; row 1 is the
  // broadcast-zero row for phantom A lanes and must stay zero forever)
  for (int i = tid; i < 2 * 16 * 264; i += 512) ((unsigned short*)h_lds)[i] = 0;

  // LDS weights: K-chunks 6,7 (B-frag layout)
#pragma unroll
  for (int gl = 0; gl < 2; ++gl)
#pragma unroll
    for (int nt = 0; nt < 4; ++nt)
#pragma unroll
      for (int kcl = 0; kcl < 2; ++kcl) {
        const int oj = nt * 256 + w * 32 + 2 * n + gl;
        const f32x4* wp = (const f32x4*)(Whh + (size_t)oj * HID + (6 + kcl) * 32 + quad * 8);
        *(short8*)&wlds[w][gl][nt][kcl][lane][0] = pack2(wp[0], wp[1]);
      }

  // register weights: K-chunks 0..5.  B[k][col=n] = Whh[oj(n)][k].
  short8 bfr[2][4][6];
#pragma unroll
  for (int gl = 0; gl < 2; ++gl)
#pragma unroll
    for (int nt = 0; nt < 4; ++nt) {
      const int oj = nt * 256 + w * 32 + 2 * n + gl;
      const float* wrow = Whh + (size_t)oj * HID;
#pragma unroll
      for (int kc = 0; kc < 6; ++kc) {
        const f32x4* wp = (const f32x4*)(wrow + kc * 32 + quad * 8);
        bfr[gl][nt][kc] = pack2(wp[0], wp[1]);
      }
    }

  float cst[2];
  cst[0] = 0.f; cst[1] = 0.f;

  __syncthreads();   // zpos, xoff, h(0), wlds ready
  const int idxq = zpos[quad] - 1;             // last valid t for this lane's row

  // per-lane constant byte offsets into h_lds
  // A-read: real lanes (n%4==0) -> row n, k-slice quad; others -> row 1 (zero,
  // broadcast). h-write: row quad*4, units u0=w*32+2n, u0+1 packed as b32.
  const int ard = ((n & 3) == 0) ? (n * 528 + quad * 16) : 528;
  const int awr = quad * 2112 + (w * 32 + 2 * n) * 2;
  const unsigned lanewx = (unsigned)((w * 32 + 2 * n) * 4);
  char* hb = (char*)&h_lds[0][0][0];
  unsigned hoff = 0;                           // read-buffer byte offset; write = hoff^8448

  // initial Wx load (t=0, both gl in one 16B load) + offset for t=1
  ushort8_t wx8 = *(const ushort8_t*)(Wx + (size_t)(unsigned)xoff[quad][0] + lanewx);
  int toko = xoff[quad][1];

  // fused pointwise (R8-validated, 5 exp + 3 rcp):
  //   c' = c*rcp(1+e^-f) + (e^{2g}-1)*rcp((1+e^-i)(e^{2g}+1))
  //   h  = (e^{2c'}-1)*rcp((1+e^-o)(e^{2c'}+1))
  for (int t = 0; t < TSEQ; ++t) {
    const int tnn = (t + 2 < TSEQ) ? (t + 2) : (TSEQ - 1);

    // acc init from prefetched Wx (has both biases); loop-local, full init:
    // only element 0 (C row quad*4) carries a real batch row.
    f32x4 acc[2][4];
#pragma unroll
    for (int gl = 0; gl < 2; ++gl)
#pragma unroll
      for (int nt = 0; nt < 4; ++nt)
        acc[gl][nt] = (f32x4){bf2f(wx8[gl * 4 + nt]), 0.f, 0.f, 0.f};

    // re-issue Wx prefetch for t+1 (consumed next step -> full-step overlap)
    wx8 = *(const ushort8_t*)(Wx + (size_t)(unsigned)toko + lanewx);
    // token offset for t+2: LDS broadcast read (lgkm, drained by the barrier)
    const int tok_next = xoff[quad][tnn];

    // merged GEMM: each A-frag read once, feeds 8 MFMAs (2gl x 4nt).
    // K-chunks 0..5 from register B-frags
#pragma unroll
    for (int kc = 0; kc < 6; ++kc) {
      const short8 a = *(const short8*)(hb + hoff + ard + kc * 64);
#pragma unroll
      for (int gl = 0; gl < 2; ++gl)
#pragma unroll
        for (int nt = 0; nt < 4; ++nt)
          acc[gl][nt] = __builtin_amdgcn_mfma_f32_16x16x32_bf16(a, bfr[gl][nt][kc], acc[gl][nt], 0, 0, 0);
    }
    // K-chunks 6..7 from LDS B-frags
#pragma unroll
    for (int kcl = 0; kcl < 2; ++kcl) {
      const short8 a = *(const short8*)(hb + hoff + ard + (6 + kcl) * 64);
#pragma unroll
      for (int gl = 0; gl < 2; ++gl)
#pragma unroll
        for (int nt = 0; nt < 4; ++nt) {
          const short8 b = *(const short8*)&wlds[w][gl][nt][kcl][lane][0];
          acc[gl][nt] = __builtin_amdgcn_mfma_f32_16x16x32_bf16(a, b, acc[gl][nt], 0, 0, 0);
        }
    }

    toko = tok_next;

    // fused pointwise, both gl, then one packed h-write
    float hv2[2];
#pragma unroll
    for (int gl = 0; gl < 2; ++gl) {
      const float ei = __expf(-acc[gl][0][0]), ef = __expf(-acc[gl][1][0]);
      const float eg2 = __expf(2.0f * acc[gl][2][0]), eo = __expf(-acc[gl][3][0]);
      const float r1 = __builtin_amdgcn_rcpf(1.0f + ef);
      const float r2 = __builtin_amdgcn_rcpf((1.0f + ei) * (eg2 + 1.0f));
      const float ci = cst[gl] * r1 + (eg2 - 1.0f) * r2;
      cst[gl] = ci;
      const float ec2 = __expf(2.0f * ci);
      const float r3 = __builtin_amdgcn_rcpf((1.0f + eo) * (ec2 + 1.0f));
      hv2[gl] = (ec2 - 1.0f) * r3;
    }
    const unsigned pk = (unsigned)f2bf(hv2[0]) | ((unsigned)f2bf(hv2[1]) << 16);
    *(unsigned*)(hb + (hoff ^ 8448u) + awr) = pk;

    // gathered last-valid h: fires once per row over the 512 steps
    if (t == idxq) {
      const size_t o0 = (size_t)(rowbase + quad) * HID + (w * 32 + 2 * n);
      lastH[o0] = hv2[0];
      lastH[o0 + 1] = hv2[1];
    }

    hoff ^= 8448u;
    barrier_lds_only();  // h(t+1) complete; global prefetches stay in flight
  }
}

// ---------------------------------------------------------------------------
// K3: logits + softmax. One wave per batch row; lane j = output j.
// ---------------------------------------------------------------------------
__global__ __launch_bounds__(64) void head_k3(
    const float* __restrict__ lastH, const float* __restrict__ Wout,
    const float* __restrict__ bout, float* __restrict__ out) {
  const int b = blockIdx.x, j = threadIdx.x;
  const f32x4* hv = (const f32x4*)(lastH + (size_t)b * HID);
  const f32x4* wv = (const f32x4*)(Wout + (size_t)j * HID);
  float acc = bout[j];
#pragma unroll 8
  for (int k = 0; k < HID / 4; ++k) {
    const f32x4 a = hv[k], ww = wv[k];
    acc += a[0] * ww[0] + a[1] * ww[1] + a[2] * ww[2] + a[3] * ww[3];
  }
  float m = acc;
  for (int s = 32; s > 0; s >>= 1) m = fmaxf(m, __shfl_xor(m, s, 64));
  const float e = __expf(acc - m);
  float ssum = e;
  for (int s = 32; s > 0; s >>= 1) ssum += __shfl_xor(ssum, s, 64);
  out[(size_t)b * OUTD + j] = e / ssum;
}

// ---------------------------------------------------------------------------
extern "C" void kernel_launch(void* const* d_in, const int* in_sizes, int n_in,
                              void* d_out, int out_size, void* d_ws, size_t ws_size,
                              hipStream_t stream) {
  const int*   x    = (const int*)d_in[0];
  const float* emb  = (const float*)d_in[1];
  const float* Wih  = (const float*)d_in[2];
  const float* Whh  = (const float*)d_in[3];
  const float* bih  = (const float*)d_in[4];
  const float* bhh  = (const float*)d_in[5];
  const float* Wout = (const float*)d_in[6];
  const float* bout = (const float*)d_in[7];
  float* out = (float*)d_out;

  // workspace carve (~97.9 MiB)
  char* ws = (char*)d_ws;
  unsigned short* Wx = (unsigned short*)ws;                 // 102,400,000 B
  float* lastH = (float*)(ws + 102400000);                  // 262,144 B

  hipLaunchKernelGGL(wx_k1, dim3(196, 4), dim3(256), 0, stream,
                     emb, Wih, bih, bhh, Wx);
  hipLaunchKernelGGL(lstm_k2, dim3(64), dim3(512), 0, stream,
                     x, Whh, Wx, lastH);
  hipLaunchKernelGGL(head_k3, dim3(BATCH), dim3(OUTD), 0, stream,
                     lastH, Wout, bout, out);
}

// Round 8
// 1033.580 us; speedup vs baseline: 9.0577x; 1.0027x over previous
//
#include <hip/hip_runtime.h>
#include <stdint.h>

// Problem constants
#define VOCAB 50000
#define EMBD  128
#define HID   256
#define G4    1024   // 4*HID
#define BATCH 256
#define TSEQ  512
#define OUTD  64

typedef __attribute__((ext_vector_type(4))) float f32x4;
typedef __attribute__((ext_vector_type(8))) short short8;
typedef __attribute__((ext_vector_type(4))) unsigned short ushort4_t;
typedef __attribute__((ext_vector_type(8))) unsigned short ushort8_t;

__device__ inline unsigned short f2bf(float f) {
  unsigned u = __float_as_uint(f);
  u += 0x7fffu + ((u >> 16) & 1u);     // round-nearest-even
  return (unsigned short)(u >> 16);
}
__device__ inline float bf2f(unsigned short u) {
  return __uint_as_float(((unsigned)u) << 16);
}
__device__ inline short8 pack2(f32x4 a, f32x4 b) {
  short8 r;
  r[0] = (short)f2bf(a[0]); r[1] = (short)f2bf(a[1]);
  r[2] = (short)f2bf(a[2]); r[3] = (short)f2bf(a[3]);
  r[4] = (short)f2bf(b[0]); r[5] = (short)f2bf(b[1]);
  r[6] = (short)f2bf(b[2]); r[7] = (short)f2bf(b[3]);
  return r;
}

// LDS-only barrier: h double-buffer needs only LDS ordering; global prefetch
// loads stay in flight across it.
__device__ inline void barrier_lds_only() {
  asm volatile("s_waitcnt lgkmcnt(0)\n\ts_barrier" ::: "memory");
}

// Wx layout: Wx[v][u*4 + nt], u = h-unit, nt in {i,f,g,o}; oj = nt*256 + u.

// ---------------------------------------------------------------------------
// K1: Wx[v][u*4+nt] = bf16( b_ih[oj] + b_hh[oj] + emb[v] . W_ih[oj] )
// R17: LDS-shared emb pack. The 4 waves previously each packed the SAME
// 16x128 emb tile (af depends on lane only). Now wave w1 packs K-chunk w1
// into a double-buffered LDS tile (1 barrier/tile); all waves read af frags
// from LDS. Per-tile pack VALU and emb loads both fall 4x; af bytes are
// bit-identical. Pad row to 136 shorts -> the b128 read pattern is a free
// 2-way bank conflict.
// ---------------------------------------------------------------------------
__global__ __launch_bounds__(256) void wx_k1(
    const float* __restrict__ emb, const float* __restrict__ Wih,
    const float* __restrict__ bih, const float* __restrict__ bhh,
    unsigned short* __restrict__ Wx) {
  const int w1 = threadIdx.x >> 6, lane = threadIdx.x & 63;
  const int quad = lane >> 4, n = lane & 15;
  const int combo = blockIdx.y * 4 + w1;        // 0..15 -> units combo*16..+15

  __shared__ __attribute__((aligned(16))) unsigned short etile[2][16][136]; // 8.5 KB

  float bias[4];
  short8 bfr[4][4];
#pragma unroll
  for (int nt = 0; nt < 4; ++nt) {
    const int oj = nt * 256 + combo * 16 + n;
    bias[nt] = bih[oj] + bhh[oj];
#pragma unroll
    for (int kc = 0; kc < 4; ++kc) {
      const f32x4* wp = (const f32x4*)(Wih + (size_t)oj * EMBD + kc * 32 + quad * 8);
      bfr[nt][kc] = pack2(wp[0], wp[1]);
    }
  }

  // prologue: pack tile 0 (wave w1 packs K-chunk w1)
  {
    const int vb0 = blockIdx.x * 256;
    const f32x4* ep = (const f32x4*)(emb + (size_t)(vb0 + n) * EMBD + w1 * 32 + quad * 8);
    *(short8*)&etile[0][n][w1 * 32 + quad * 8] = pack2(ep[0], ep[1]);
  }

  for (int vt = 0; vt < 16; ++vt) {
    const int vb = blockIdx.x * 256 + vt * 16;
    if (vb >= VOCAB) break;                     // uniform per block: no barrier divergence
    __syncthreads();                            // buf[vt&1] ready; buf[(vt+1)&1] free
    const int vbn = vb + 16;
    if (vt < 15 && vbn < VOCAB) {               // pack next tile into other buffer
      const f32x4* ep = (const f32x4*)(emb + (size_t)(vbn + n) * EMBD + w1 * 32 + quad * 8);
      *(short8*)&etile[(vt + 1) & 1][n][w1 * 32 + quad * 8] = pack2(ep[0], ep[1]);
    }
    short8 af[4];
#pragma unroll
    for (int kc = 0; kc < 4; ++kc)
      af[kc] = *(const short8*)&etile[vt & 1][n][kc * 32 + quad * 8];
    f32x4 acc[4];
#pragma unroll
    for (int nt = 0; nt < 4; ++nt) acc[nt] = (f32x4){0.f, 0.f, 0.f, 0.f};
#pragma unroll
    for (int kc = 0; kc < 4; ++kc)
#pragma unroll
      for (int nt = 0; nt < 4; ++nt)
        acc[nt] = __builtin_amdgcn_mfma_f32_16x16x32_bf16(af[kc], bfr[nt][kc], acc[nt], 0, 0, 0);
#pragma unroll
    for (int rr = 0; rr < 4; ++rr) {
      ushort4_t o;
#pragma unroll
      for (int nt = 0; nt < 4; ++nt) o[nt] = f2bf(acc[nt][rr] + bias[nt]);
      *(ushort4_t*)&Wx[(size_t)(vb + quad * 4 + rr) * G4 + (combo * 16 + n) * 4] = o;
    }
  }
}

// ---------------------------------------------------------------------------
// K2: LSTM recurrence (R13 core, byte-identical per-step loop) + fused head.
// Capacity lessons locked in: R14 (all-reg Whh spills — full Whh = whole CU
// register file; 6-reg/2-LDS split optimal), R15 (per-step cross-WG exchange
// unaffordable — per-XCD L2s non-coherent).
// R17 deltas: in-loop lastH global store -> 2 cndmask into lastreg; after the
// t-loop, stage 4x256 last-h in (reused) h_lds and compute logits+softmax
// (former K3, same op order -> bit-identical), saving one kernel launch.
// ---------------------------------------------------------------------------
__global__ __launch_bounds__(512, 2) void lstm_k2(
    const int* __restrict__ x, const float* __restrict__ Whh,
    const unsigned short* __restrict__ Wx,
    const float* __restrict__ Wout, const float* __restrict__ bout,
    float* __restrict__ out) {                 // [256][64]
  const int group = blockIdx.x;                // 64 groups of 4 batch rows
  const int rowbase = group * 4;
  const int tid = threadIdx.x;
  const int w = tid >> 6, lane = tid & 63;
  const int quad = lane >> 4, n = lane & 15;

  __shared__ __attribute__((aligned(16))) unsigned short h_lds[2][16][264];   // 16.5 KB
  __shared__ __attribute__((aligned(16))) unsigned short wlds[8][2][4][2][64][8]; // 128 KB
  __shared__ int xoff[4][TSEQ];                // 8 KB, prescaled token offsets
  __shared__ int zpos[4];

  if (tid < 4) zpos[tid] = 1 << 30;
  __syncthreads();
  // scan tokens: pad position + stage prescaled Wx row offsets in LDS
  for (int i = tid; i < 4 * TSEQ; i += 512) {
    const int row = i >> 9, tc = i & 511;
    const int tok = x[(size_t)(rowbase + row) * TSEQ + tc];
    if (tok == 0) atomicMin(&zpos[row], tc);
    xoff[row][tc] = tok * G4;
  }
  // zero BOTH h buffers (real rows 0,4,8,12 need h(0)=0; row 1 is the
  // broadcast-zero row for phantom A lanes and must stay zero forever)
  for (int i = tid; i < 2 * 16 * 264; i += 512) ((unsigned short*)h_lds)[i] = 0;

  // LDS weights: K-chunks 6,7 (B-frag layout)
#pragma unroll
  for (int gl = 0; gl < 2; ++gl)
#pragma unroll
    for (int nt = 0; nt < 4; ++nt)
#pragma unroll
      for (int kcl = 0; kcl < 2; ++kcl) {
        const int oj = nt * 256 + w * 32 + 2 * n + gl;
        const f32x4* wp = (const f32x4*)(Whh + (size_t)oj * HID + (6 + kcl) * 32 + quad * 8);
        *(short8*)&wlds[w][gl][nt][kcl][lane][0] = pack2(wp[0], wp[1]);
      }

  // register weights: K-chunks 0..5.  B[k][col=n] = Whh[oj(n)][k].
  short8 bfr[2][4][6];
#pragma unroll
  for (int gl = 0; gl < 2; ++gl)
#pragma unroll
    for (int nt = 0; nt < 4; ++nt) {
      const int oj = nt * 256 + w * 32 + 2 * n + gl;
      const float* wrow = Whh + (size_t)oj * HID;
#pragma unroll
      for (int kc = 0; kc < 6; ++kc) {
        const f32x4* wp = (const f32x4*)(wrow + kc * 32 + quad * 8);
        bfr[gl][nt][kc] = pack2(wp[0], wp[1]);
      }
    }

  float cst[2], lastreg[2];
  cst[0] = 0.f; cst[1] = 0.f;
  lastreg[0] = 0.f; lastreg[1] = 0.f;

  __syncthreads();   // zpos, xoff, h(0), wlds ready
  const int idxq = zpos[quad] - 1;             // last valid t for this lane's row

  // per-lane constant byte offsets into h_lds
  const int ard = ((n & 3) == 0) ? (n * 528 + quad * 16) : 528;
  const int awr = quad * 2112 + (w * 32 + 2 * n) * 2;
  const unsigned lanewx = (unsigned)((w * 32 + 2 * n) * 4);
  char* hb = (char*)&h_lds[0][0][0];
  unsigned hoff = 0;                           // read-buffer byte offset; write = hoff^8448

  // initial Wx load (t=0, both gl in one 16B load) + offset for t=1
  ushort8_t wx8 = *(const ushort8_t*)(Wx + (size_t)(unsigned)xoff[quad][0] + lanewx);
  int toko = xoff[quad][1];

  // fused pointwise (R8-validated, 5 exp + 3 rcp):
  //   c' = c*rcp(1+e^-f) + (e^{2g}-1)*rcp((1+e^-i)(e^{2g}+1))
  //   h  = (e^{2c'}-1)*rcp((1+e^-o)(e^{2c'}+1))
  for (int t = 0; t < TSEQ; ++t) {
    const int tnn = (t + 2 < TSEQ) ? (t + 2) : (TSEQ - 1);

    f32x4 acc[2][4];
#pragma unroll
    for (int gl = 0; gl < 2; ++gl)
#pragma unroll
      for (int nt = 0; nt < 4; ++nt)
        acc[gl][nt] = (f32x4){bf2f(wx8[gl * 4 + nt]), 0.f, 0.f, 0.f};

    // re-issue Wx prefetch for t+1 (consumed next step -> full-step overlap)
    wx8 = *(const ushort8_t*)(Wx + (size_t)(unsigned)toko + lanewx);
    const int tok_next = xoff[quad][tnn];

    // merged GEMM: each A-frag read once, feeds 8 MFMAs (2gl x 4nt).
#pragma unroll
    for (int kc = 0; kc < 6; ++kc) {
      const short8 a = *(const short8*)(hb + hoff + ard + kc * 64);
#pragma unroll
      for (int gl = 0; gl < 2; ++gl)
#pragma unroll
        for (int nt = 0; nt < 4; ++nt)
          acc[gl][nt] = __builtin_amdgcn_mfma_f32_16x16x32_bf16(a, bfr[gl][nt][kc], acc[gl][nt], 0, 0, 0);
    }
#pragma unroll
    for (int kcl = 0; kcl < 2; ++kcl) {
      const short8 a = *(const short8*)(hb + hoff + ard + (6 + kcl) * 64);
#pragma unroll
      for (int gl = 0; gl < 2; ++gl)
#pragma unroll
        for (int nt = 0; nt < 4; ++nt) {
          const short8 b = *(const short8*)&wlds[w][gl][nt][kcl][lane][0];
          acc[gl][nt] = __builtin_amdgcn_mfma_f32_16x16x32_bf16(a, b, acc[gl][nt], 0, 0, 0);
        }
    }

    toko = tok_next;

    // fused pointwise, both gl, then one packed h-write
    float hv2[2];
#pragma unroll
    for (int gl = 0; gl < 2; ++gl) {
      const float ei = __expf(-acc[gl][0][0]), ef = __expf(-acc[gl][1][0]);
      const float eg2 = __expf(2.0f * acc[gl][2][0]), eo = __expf(-acc[gl][3][0]);
      const float r1 = __builtin_amdgcn_rcpf(1.0f + ef);
      const float r2 = __builtin_amdgcn_rcpf((1.0f + ei) * (eg2 + 1.0f));
      const float ci = cst[gl] * r1 + (eg2 - 1.0f) * r2;
      cst[gl] = ci;
      const float ec2 = __expf(2.0f * ci);
      const float r3 = __builtin_amdgcn_rcpf((1.0f + eo) * (ec2 + 1.0f));
      hv2[gl] = (ec2 - 1.0f) * r3;
      lastreg[gl] = (t == idxq) ? hv2[gl] : lastreg[gl];   // gathered last-valid h
    }
    const unsigned pk = (unsigned)f2bf(hv2[0]) | ((unsigned)f2bf(hv2[1]) << 16);
    *(unsigned*)(hb + (hoff ^ 8448u) + awr) = pk;

    hoff ^= 8448u;
    barrier_lds_only();  // h(t+1) complete; global prefetches stay in flight
  }

  // ---- fused head (former K3), bit-identical op order ----
  __syncthreads();                              // recurrence done; reuse h_lds
  float* hfin = (float*)&h_lds[0][0][0];        // 4 x 256 f32 = 4 KB
  {
    const int u0 = w * 32 + 2 * n;
    hfin[quad * HID + u0] = lastreg[0];
    hfin[quad * HID + u0 + 1] = lastreg[1];
  }
  __syncthreads();
  if (tid < 256) {                              // wave r = row rowbase+r; lane j = output j
    const int r = tid >> 6, j = tid & 63;
    const float* hr = hfin + r * HID;
    const f32x4* wv = (const f32x4*)(Wout + (size_t)j * HID);
    float acc = bout[j];
#pragma unroll 8
    for (int k = 0; k < HID / 4; ++k) {
      const f32x4 a = *(const f32x4*)(hr + 4 * k);  // LDS broadcast read
      const f32x4 ww = wv[k];
      acc += a[0] * ww[0] + a[1] * ww[1] + a[2] * ww[2] + a[3] * ww[3];
    }
    float m = acc;
    for (int s = 32; s > 0; s >>= 1) m = fmaxf(m, __shfl_xor(m, s, 64));
    const float e = __expf(acc - m);
    float ssum = e;
    for (int s = 32; s > 0; s >>= 1) ssum += __shfl_xor(ssum, s, 64);
    out[(size_t)(rowbase + r) * OUTD + j] = e / ssum;
  }
}

// ---------------------------------------------------------------------------
extern "C" void kernel_launch(void* const* d_in, const int* in_sizes, int n_in,
                              void* d_out, int out_size, void* d_ws, size_t ws_size,
                              hipStream_t stream) {
  const int*   x    = (const int*)d_in[0];
  const float* emb  = (const float*)d_in[1];
  const float* Wih  = (const float*)d_in[2];
  const float* Whh  = (const float*)d_in[3];
  const float* bih  = (const float*)d_in[4];
  const float* bhh  = (const float*)d_in[5];
  const float* Wout = (const float*)d_in[6];
  const float* bout = (const float*)d_in[7];
  float* out = (float*)d_out;

  // workspace carve (~97.7 MiB)
  char* ws = (char*)d_ws;
  unsigned short* Wx = (unsigned short*)ws;                 // 102,400,000 B

  hipLaunchKernelGGL(wx_k1, dim3(196, 4), dim3(256), 0, stream,
                     emb, Wih, bih, bhh, Wx);
  hipLaunchKernelGGL(lstm_k2, dim3(64), dim3(512), 0, stream,
                     x, Whh, Wx, Wout, bout, out);
}

// Round 9
// 1006.067 us; speedup vs baseline: 9.3054x; 1.0273x over previous
//
#include <hip/hip_runtime.h>
#include <stdint.h>

// Problem constants
#define VOCAB 50000
#define EMBD  128
#define HID   256
#define G4    1024   // 4*HID
#define BATCH 256
#define TSEQ  512
#define OUTD  64

typedef __attribute__((ext_vector_type(4))) float f32x4;
typedef __attribute__((ext_vector_type(8))) short short8;
typedef __attribute__((ext_vector_type(4))) unsigned short ushort4_t;
typedef __attribute__((ext_vector_type(8))) unsigned short ushort8_t;

__device__ inline unsigned short f2bf(float f) {
  unsigned u = __float_as_uint(f);
  u += 0x7fffu + ((u >> 16) & 1u);     // round-nearest-even
  return (unsigned short)(u >> 16);
}
__device__ inline float bf2f(unsigned short u) {
  return __uint_as_float(((unsigned)u) << 16);
}
__device__ inline short8 pack2(f32x4 a, f32x4 b) {
  short8 r;
  r[0] = (short)f2bf(a[0]); r[1] = (short)f2bf(a[1]);
  r[2] = (short)f2bf(a[2]); r[3] = (short)f2bf(a[3]);
  r[4] = (short)f2bf(b[0]); r[5] = (short)f2bf(b[1]);
  r[6] = (short)f2bf(b[2]); r[7] = (short)f2bf(b[3]);
  return r;
}

// LDS-only barrier: h double-buffer needs only LDS ordering; global prefetch
// loads stay in flight across it.
__device__ inline void barrier_lds_only() {
  asm volatile("s_waitcnt lgkmcnt(0)\n\ts_barrier" ::: "memory");
}

// Wx layout: Wx[v][u*4 + nt], u = h-unit, nt in {i,f,g,o}; oj = nt*256 + u.

// ---------------------------------------------------------------------------
// K1: Wx[v][u*4+nt] = bf16( b_ih[oj] + b_hh[oj] + emb[v] . W_ih[oj] )
// R17 version (kept — measured ~32 us faster than R16): LDS-shared emb pack.
// Wave w1 packs K-chunk w1 into a double-buffered LDS tile (1 barrier/tile);
// all waves read af frags from LDS. 4x less pack VALU + emb fetch;
// af bytes bit-identical.
// ---------------------------------------------------------------------------
__global__ __launch_bounds__(256) void wx_k1(
    const float* __restrict__ emb, const float* __restrict__ Wih,
    const float* __restrict__ bih, const float* __restrict__ bhh,
    unsigned short* __restrict__ Wx) {
  const int w1 = threadIdx.x >> 6, lane = threadIdx.x & 63;
  const int quad = lane >> 4, n = lane & 15;
  const int combo = blockIdx.y * 4 + w1;        // 0..15 -> units combo*16..+15

  __shared__ __attribute__((aligned(16))) unsigned short etile[2][16][136]; // 8.5 KB

  float bias[4];
  short8 bfr[4][4];
#pragma unroll
  for (int nt = 0; nt < 4; ++nt) {
    const int oj = nt * 256 + combo * 16 + n;
    bias[nt] = bih[oj] + bhh[oj];
#pragma unroll
    for (int kc = 0; kc < 4; ++kc) {
      const f32x4* wp = (const f32x4*)(Wih + (size_t)oj * EMBD + kc * 32 + quad * 8);
      bfr[nt][kc] = pack2(wp[0], wp[1]);
    }
  }

  // prologue: pack tile 0 (wave w1 packs K-chunk w1)
  {
    const int vb0 = blockIdx.x * 256;
    const f32x4* ep = (const f32x4*)(emb + (size_t)(vb0 + n) * EMBD + w1 * 32 + quad * 8);
    *(short8*)&etile[0][n][w1 * 32 + quad * 8] = pack2(ep[0], ep[1]);
  }

  for (int vt = 0; vt < 16; ++vt) {
    const int vb = blockIdx.x * 256 + vt * 16;
    if (vb >= VOCAB) break;                     // uniform per block: no barrier divergence
    __syncthreads();                            // buf[vt&1] ready; buf[(vt+1)&1] free
    const int vbn = vb + 16;
    if (vt < 15 && vbn < VOCAB) {               // pack next tile into other buffer
      const f32x4* ep = (const f32x4*)(emb + (size_t)(vbn + n) * EMBD + w1 * 32 + quad * 8);
      *(short8*)&etile[(vt + 1) & 1][n][w1 * 32 + quad * 8] = pack2(ep[0], ep[1]);
    }
    short8 af[4];
#pragma unroll
    for (int kc = 0; kc < 4; ++kc)
      af[kc] = *(const short8*)&etile[vt & 1][n][kc * 32 + quad * 8];
    f32x4 acc[4];
#pragma unroll
    for (int nt = 0; nt < 4; ++nt) acc[nt] = (f32x4){0.f, 0.f, 0.f, 0.f};
#pragma unroll
    for (int kc = 0; kc < 4; ++kc)
#pragma unroll
      for (int nt = 0; nt < 4; ++nt)
        acc[nt] = __builtin_amdgcn_mfma_f32_16x16x32_bf16(af[kc], bfr[nt][kc], acc[nt], 0, 0, 0);
#pragma unroll
    for (int rr = 0; rr < 4; ++rr) {
      ushort4_t o;
#pragma unroll
      for (int nt = 0; nt < 4; ++nt) o[nt] = f2bf(acc[nt][rr] + bias[nt]);
      *(ushort4_t*)&Wx[(size_t)(vb + quad * 4 + rr) * G4 + (combo * 16 + n) * 4] = o;
    }
  }
}

// ---------------------------------------------------------------------------
// K2: LSTM recurrence — byte-identical to R13's loop (measured 892-894 us).
// R17's fused head + lastreg cndmask regressed THIS loop +30 us (rule-19
// co-codegen perturbation: appended tail changed hot-loop regalloc/schedule)
// while saving only ~4 us of launch — unbundled back out.
// Capacity lessons locked in: R14 (all-reg Whh spills; 6-reg/2-LDS optimal),
// R15 (per-step cross-WG exchange unaffordable; per-XCD L2 non-coherent).
// ---------------------------------------------------------------------------
__global__ __launch_bounds__(512, 2) void lstm_k2(
    const int* __restrict__ x, const float* __restrict__ Whh,
    const unsigned short* __restrict__ Wx,
    float* __restrict__ lastH) {               // [256][256]
  const int group = blockIdx.x;                // 64 groups of 4 batch rows
  const int rowbase = group * 4;
  const int tid = threadIdx.x;
  const int w = tid >> 6, lane = tid & 63;
  const int quad = lane >> 4, n = lane & 15;

  __shared__ __attribute__((aligned(16))) unsigned short h_lds[2][16][264];   // 16.5 KB
  __shared__ __attribute__((aligned(16))) unsigned short wlds[8][2][4][2][64][8]; // 128 KB
  __shared__ int xoff[4][TSEQ];                // 8 KB, prescaled token offsets
  __shared__ int zpos[4];

  if (tid < 4) zpos[tid] = 1 << 30;
  __syncthreads();
  // scan tokens: pad position + stage prescaled Wx row offsets in LDS
  for (int i = tid; i < 4 * TSEQ; i += 512) {
    const int row = i >> 9, tc = i & 511;
    const int tok = x[(size_t)(rowbase + row) * TSEQ + tc];
    if (tok == 0) atomicMin(&zpos[row], tc);
    xoff[row][tc] = tok * G4;
  }
  // zero BOTH h buffers (real rows 0,4,8,12 need h(0)=0; row 1 is the
  // broadcast-zero row for phantom A lanes and must stay zero forever)
  for (int i = tid; i < 2 * 16 * 264; i += 512) ((unsigned short*)h_lds)[i] = 0;

  // LDS weights: K-chunks 6,7 (B-frag layout)
#pragma unroll
  for (int gl = 0; gl < 2; ++gl)
#pragma unroll
    for (int nt = 0; nt < 4; ++nt)
#pragma unroll
      for (int kcl = 0; kcl < 2; ++kcl) {
        const int oj = nt * 256 + w * 32 + 2 * n + gl;
        const f32x4* wp = (const f32x4*)(Whh + (size_t)oj * HID + (6 + kcl) * 32 + quad * 8);
        *(short8*)&wlds[w][gl][nt][kcl][lane][0] = pack2(wp[0], wp[1]);
      }

  // register weights: K-chunks 0..5.  B[k][col=n] = Whh[oj(n)][k].
  short8 bfr[2][4][6];
#pragma unroll
  for (int gl = 0; gl < 2; ++gl)
#pragma unroll
    for (int nt = 0; nt < 4; ++nt) {
      const int oj = nt * 256 + w * 32 + 2 * n + gl;
      const float* wrow = Whh + (size_t)oj * HID;
#pragma unroll
      for (int kc = 0; kc < 6; ++kc) {
        const f32x4* wp = (const f32x4*)(wrow + kc * 32 + quad * 8);
        bfr[gl][nt][kc] = pack2(wp[0], wp[1]);
      }
    }

  float cst[2];
  cst[0] = 0.f; cst[1] = 0.f;

  __syncthreads();   // zpos, xoff, h(0), wlds ready
  const int idxq = zpos[quad] - 1;             // last valid t for this lane's row

  // per-lane constant byte offsets into h_lds
  // A-read: real lanes (n%4==0) -> row n, k-slice quad; others -> row 1 (zero,
  // broadcast). h-write: row quad*4, units u0=w*32+2n, u0+1 packed as b32.
  const int ard = ((n & 3) == 0) ? (n * 528 + quad * 16) : 528;
  const int awr = quad * 2112 + (w * 32 + 2 * n) * 2;
  const unsigned lanewx = (unsigned)((w * 32 + 2 * n) * 4);
  char* hb = (char*)&h_lds[0][0][0];
  unsigned hoff = 0;                           // read-buffer byte offset; write = hoff^8448

  // initial Wx load (t=0, both gl in one 16B load) + offset for t=1
  ushort8_t wx8 = *(const ushort8_t*)(Wx + (size_t)(unsigned)xoff[quad][0] + lanewx);
  int toko = xoff[quad][1];

  // fused pointwise (R8-validated, 5 exp + 3 rcp):
  //   c' = c*rcp(1+e^-f) + (e^{2g}-1)*rcp((1+e^-i)(e^{2g}+1))
  //   h  = (e^{2c'}-1)*rcp((1+e^-o)(e^{2c'}+1))
  for (int t = 0; t < TSEQ; ++t) {
    const int tnn = (t + 2 < TSEQ) ? (t + 2) : (TSEQ - 1);

    // acc init from prefetched Wx (has both biases); loop-local, full init:
    // only element 0 (C row quad*4) carries a real batch row.
    f32x4 acc[2][4];
#pragma unroll
    for (int gl = 0; gl < 2; ++gl)
#pragma unroll
      for (int nt = 0; nt < 4; ++nt)
        acc[gl][nt] = (f32x4){bf2f(wx8[gl * 4 + nt]), 0.f, 0.f, 0.f};

    // re-issue Wx prefetch for t+1 (consumed next step -> full-step overlap)
    wx8 = *(const ushort8_t*)(Wx + (size_t)(unsigned)toko + lanewx);
    // token offset for t+2: LDS broadcast read (lgkm, drained by the barrier)
    const int tok_next = xoff[quad][tnn];

    // merged GEMM: each A-frag read once, feeds 8 MFMAs (2gl x 4nt).
    // K-chunks 0..5 from register B-frags
#pragma unroll
    for (int kc = 0; kc < 6; ++kc) {
      const short8 a = *(const short8*)(hb + hoff + ard + kc * 64);
#pragma unroll
      for (int gl = 0; gl < 2; ++gl)
#pragma unroll
        for (int nt = 0; nt < 4; ++nt)
          acc[gl][nt] = __builtin_amdgcn_mfma_f32_16x16x32_bf16(a, bfr[gl][nt][kc], acc[gl][nt], 0, 0, 0);
    }
    // K-chunks 6..7 from LDS B-frags
#pragma unroll
    for (int kcl = 0; kcl < 2; ++kcl) {
      const short8 a = *(const short8*)(hb + hoff + ard + (6 + kcl) * 64);
#pragma unroll
      for (int gl = 0; gl < 2; ++gl)
#pragma unroll
        for (int nt = 0; nt < 4; ++nt) {
          const short8 b = *(const short8*)&wlds[w][gl][nt][kcl][lane][0];
          acc[gl][nt] = __builtin_amdgcn_mfma_f32_16x16x32_bf16(a, b, acc[gl][nt], 0, 0, 0);
        }
    }

    toko = tok_next;

    // fused pointwise, both gl, then one packed h-write
    float hv2[2];
#pragma unroll
    for (int gl = 0; gl < 2; ++gl) {
      const float ei = __expf(-acc[gl][0][0]), ef = __expf(-acc[gl][1][0]);
      const float eg2 = __expf(2.0f * acc[gl][2][0]), eo = __expf(-acc[gl][3][0]);
      const float r1 = __builtin_amdgcn_rcpf(1.0f + ef);
      const float r2 = __builtin_amdgcn_rcpf((1.0f + ei) * (eg2 + 1.0f));
      const float ci = cst[gl] * r1 + (eg2 - 1.0f) * r2;
      cst[gl] = ci;
      const float ec2 = __expf(2.0f * ci);
      const float r3 = __builtin_amdgcn_rcpf((1.0f + eo) * (ec2 + 1.0f));
      hv2[gl] = (ec2 - 1.0f) * r3;
    }
    const unsigned pk = (unsigned)f2bf(hv2[0]) | ((unsigned)f2bf(hv2[1]) << 16);
    *(unsigned*)(hb + (hoff ^ 8448u) + awr) = pk;

    // gathered last-valid h: fires once per row over the 512 steps
    if (t == idxq) {
      const size_t o0 = (size_t)(rowbase + quad) * HID + (w * 32 + 2 * n);
      lastH[o0] = hv2[0];
      lastH[o0 + 1] = hv2[1];
    }

    hoff ^= 8448u;
    barrier_lds_only();  // h(t+1) complete; global prefetches stay in flight
  }
}

// ---------------------------------------------------------------------------
// K3: logits + softmax. One wave per batch row; lane j = output j.
// ---------------------------------------------------------------------------
__global__ __launch_bounds__(64) void head_k3(
    const float* __restrict__ lastH, const float* __restrict__ Wout,
    const float* __restrict__ bout, float* __restrict__ out) {
  const int b = blockIdx.x, j = threadIdx.x;
  const f32x4* hv = (const f32x4*)(lastH + (size_t)b * HID);
  const f32x4* wv = (const f32x4*)(Wout + (size_t)j * HID);
  float acc = bout[j];
#pragma unroll 8
  for (int k = 0; k < HID / 4; ++k) {
    const f32x4 a = hv[k], ww = wv[k];
    acc += a[0] * ww[0] + a[1] * ww[1] + a[2] * ww[2] + a[3] * ww[3];
  }
  float m = acc;
  for (int s = 32; s > 0; s >>= 1) m = fmaxf(m, __shfl_xor(m, s, 64));
  const float e = __expf(acc - m);
  float ssum = e;
  for (int s = 32; s > 0; s >>= 1) ssum += __shfl_xor(ssum, s, 64);
  out[(size_t)b * OUTD + j] = e / ssum;
}

// ---------------------------------------------------------------------------
extern "C" void kernel_launch(void* const* d_in, const int* in_sizes, int n_in,
                              void* d_out, int out_size, void* d_ws, size_t ws_size,
                              hipStream_t stream) {
  const int*   x    = (const int*)d_in[0];
  const float* emb  = (const float*)d_in[1];
  const float* Wih  = (const float*)d_in[2];
  const float* Whh  = (const float*)d_in[3];
  const float* bih  = (const float*)d_in[4];
  const float* bhh  = (const float*)d_in[5];
  const float* Wout = (const float*)d_in[6];
  const float* bout = (const float*)d_in[7];
  float* out = (float*)d_out;

  // workspace carve (~97.9 MiB)
  char* ws = (char*)d_ws;
  unsigned short* Wx = (unsigned short*)ws;                 // 102,400,000 B
  float* lastH = (float*)(ws + 102400000);                  // 262,144 B

  hipLaunchKernelGGL(wx_k1, dim3(196, 4), dim3(256), 0, stream,
                     emb, Wih, bih, bhh, Wx);
  hipLaunchKernelGGL(lstm_k2, dim3(64), dim3(512), 0, stream,
                     x, Whh, Wx, lastH);
  hipLaunchKernelGGL(head_k3, dim3(BATCH), dim3(OUTD), 0, stream,
                     lastH, Wout, bout, out);
}